// Round 23
// baseline (244.827 us; speedup 1.0000x reference)
//
#include <hip/hip_runtime.h>
#include <stdint.h>

// Problem constants: B=4, N=32768, K=16, nqueries=2048, stride=16.
// Geometry: block = 128 thr = 2 waves, owns FOUR queries; each wave scans
// HALF the stream for all 4 (4096 waves, same total point-visits as R9).
// Per-visit overhead (loads/addr/loop) amortized over 4 queries; |p|^2
// shared 4 ways. Shared-tau LDS exchange (R11-proven conservative) keeps
// insert counts near single-stream levels; exact 2-wave rank merge (R7).
// Gate: SoA packed v_pk_fma_f32 (R18). Accepted lanes re-verified with
// EXACT numpy-ordered distance -> bit-exact. Fallback: R9 AoS kernel.
#define NPTS  32768
#define NQ    2048
#define KNN   16
#define NB    4
#define PPL   8
#define HALF  (NPTS / 2)
#define ITERS_H (HALF / (64 * PPL))  // 32
#define GATE_MARGIN 5e-4f

typedef float f32x2 __attribute__((ext_vector_type(2)));

__device__ __forceinline__ int dpp_shr1_i(int x) {
    return __builtin_amdgcn_update_dpp(x, x, 0x111, 0xf, 0xf, false);
}
__device__ __forceinline__ float dpp_shr1_f(float x) {
    return __int_as_float(dpp_shr1_i(__float_as_int(x)));
}
__device__ __forceinline__ float readlane_f(float x, int l) {
    return __int_as_float(__builtin_amdgcn_readlane(__float_as_int(x), l));
}

__device__ __forceinline__ f32x2 pk_mul(f32x2 a, f32x2 b) {
    f32x2 d;
    asm("v_pk_mul_f32 %0, %1, %2" : "=v"(d) : "v"(a), "v"(b));
    return d;
}
__device__ __forceinline__ f32x2 pk_fma(f32x2 a, f32x2 b, f32x2 c) {
    f32x2 d;
    asm("v_pk_fma_f32 %0, %1, %2, %3" : "=v"(d) : "v"(a), "v"(b), "v"(c));
    return d;
}

// Exact distributed top-16 for list T (0..3): sorted (dist,idx) ascending in
// lanes 16T..16T+15; lane 16T+15 holds this wave's exact tau. d is the EXACT
// numpy distance. th = min(tau, partner ts) + qnm (conservative gate).
// T is compile-time constant at every call site (unrolled loops) -> folds.
__device__ __forceinline__ void insert_rt(int T, float d, int p, int lane,
                                          float& ld, int& li, float& tau,
                                          float& th, float qnm, float ts)
{
    unsigned long long rem = __ballot(d <= tau);
    while (rem) {
        const int srcl = __ffsll(rem) - 1;           // wave-uniform
        const float wd = readlane_f(d, srcl);
        const int   wi = __builtin_amdgcn_readlane(p, srcl);
        const bool less = (ld < wd) || (ld == wd && li < wi);
        const unsigned long long lm = __ballot(less);
        const int pos = __popc((unsigned)((lm >> (16 * T)) & 0xffffull));
        const float pld = dpp_shr1_f(ld);
        const int   pli = dpp_shr1_i(li);
        if ((lane >> 4) == T) {
            const int gl = lane & 15;
            if (gl == pos)      { ld = wd;  li = wi;  }
            else if (gl > pos)  { ld = pld; li = pli; }
        }
        tau = readlane_f(ld, 16 * T + 15);
        th  = fminf(tau, ts) + qnm;
        rem &= rem - 1;
        if (rem) rem &= __ballot(d <= tau);          // re-gate survivors (exact)
    }
}

// ---------------- pre-pass: AoS xyz -> SoA x[],y[],z[] ----------------
__global__ __launch_bounds__(256) void repack_soa(const float* __restrict__ xyz,
                                                  float* __restrict__ ws)
{
    const int i = blockIdx.x * 256 + threadIdx.x;    // 4-point group id
    const int b = i / (NPTS / 4);
    const int g = i % (NPTS / 4);
    const float4* src = (const float4*)(xyz + (size_t)b * NPTS * 3) + 3 * g;
    const float4 c0 = src[0], c1 = src[1], c2 = src[2];
    float* xs = ws + (size_t)b * 3 * NPTS;
    float* ys = xs + NPTS;
    float* zs = ys + NPTS;
    ((float4*)xs)[g] = make_float4(c0.x, c0.w, c1.z, c2.y);
    ((float4*)ys)[g] = make_float4(c0.y, c1.x, c1.w, c2.z);
    ((float4*)zs)[g] = make_float4(c0.z, c1.y, c2.x, c2.w);
}

// ---------------- main kernel: 4 queries / block, half stream / wave ----------------
struct PtBuf { float4 x0, x1, y0, y1, z0, z1; };

__device__ __forceinline__ void loadbuf(PtBuf& b, const float* xs,
                                        const float* ys, const float* zs,
                                        unsigned o)
{
    b.x0 = *(const float4*)(xs + o);  b.x1 = *(const float4*)(xs + o + 4);
    b.y0 = *(const float4*)(ys + o);  b.y1 = *(const float4*)(ys + o + 4);
    b.z0 = *(const float4*)(zs + o);  b.z1 = *(const float4*)(zs + o + 4);
}

// One 512-point step for 4 queries: |p|^2 shared (3 pk), per query 12 pk +
// 8 cmp-ballots; exact recompute + exact insert for accepted slots.
__device__ __forceinline__ void step4(const PtBuf& c, int pb, int lane,
                                      const f32x2* M2X, const f32x2* M2Y,
                                      const f32x2* M2Z,
                                      const float* qx, const float* qy,
                                      const float* qz,
                                      float& ld, int& li,
                                      float* tau, float* th,
                                      const float* qnm, const float* ts)
{
    f32x2 X[4] = { {c.x0.x, c.x0.y}, {c.x0.z, c.x0.w},
                   {c.x1.x, c.x1.y}, {c.x1.z, c.x1.w} };
    f32x2 Y[4] = { {c.y0.x, c.y0.y}, {c.y0.z, c.y0.w},
                   {c.y1.x, c.y1.y}, {c.y1.z, c.y1.w} };
    f32x2 Z[4] = { {c.z0.x, c.z0.y}, {c.z0.z, c.z0.w},
                   {c.z1.x, c.z1.y}, {c.z1.z, c.z1.w} };
    f32x2 S[4];
    #pragma unroll
    for (int u = 0; u < 4; ++u)
        S[u] = pk_fma(Z[u], Z[u], pk_fma(Y[u], Y[u], pk_mul(X[u], X[u])));

    #pragma unroll
    for (int t = 0; t < 4; ++t) {                    // 4 independent queries
        unsigned long long m[PPL], any = 0;
        f32x2 T0[4];
        #pragma unroll
        for (int u = 0; u < 4; ++u) {
            T0[u] = pk_fma(Z[u], M2Z[t],
                      pk_fma(Y[u], M2Y[t], pk_fma(X[u], M2X[t], S[u])));
            m[2*u]   = __ballot(T0[u].x <= th[t]);
            m[2*u+1] = __ballot(T0[u].y <= th[t]);
            any |= m[2*u] | m[2*u+1];
        }
        if (any) {
            #pragma unroll
            for (int j = 0; j < PPL; ++j) {
                if (m[j]) {                          // exact numpy distance
                    const float pxj = (j & 1) ? X[j >> 1].y : X[j >> 1].x;
                    const float pyj = (j & 1) ? Y[j >> 1].y : Y[j >> 1].x;
                    const float pzj = (j & 1) ? Z[j >> 1].y : Z[j >> 1].x;
                    const float dx = __fadd_rn(pxj, -qx[t]);
                    const float dy = __fadd_rn(pyj, -qy[t]);
                    const float dz = __fadd_rn(pzj, -qz[t]);
                    const float d  = __fadd_rn(
                        __fadd_rn(__fmul_rn(dx, dx), __fmul_rn(dy, dy)),
                        __fmul_rn(dz, dz));
                    insert_rt(t, d, pb + j, lane, ld, li,
                              tau[t], th[t], qnm[t], ts[t]);
                }
            }
        }
    }
}

// 2048 blocks x 2 waves = 4096 waves (4/SIMD, grid-limited as R9).
__global__ __launch_bounds__(128) void knn4(const float* __restrict__ ws,
                                            float* __restrict__ out_idx,
                                            float* __restrict__ out_pts)
{
    const int tid  = threadIdx.x;
    const int lane = tid & 63;
    const int h    = tid >> 6;               // half of the point stream
    const int p    = blockIdx.x;             // [0, 2048)
    const int b    = p >> 9;                 // 512 blocks per batch
    const int gg   = p & 511;                // 4-query group within batch
    const float* xs = ws + (size_t)b * 3 * NPTS;
    const float* ys = xs + NPTS;
    const float* zs = ys + NPTS;

    float qx[4], qy[4], qz[4], qnm[4], tau[4], th[4], ts[4];
    f32x2 M2X[4], M2Y[4], M2Z[4];
    #pragma unroll
    for (int t = 0; t < 4; ++t) {
        const int qp = (gg << 6) + (t << 4); // stride-16 subsample
        qx[t] = xs[qp]; qy[t] = ys[qp]; qz[t] = zs[qp];
        M2X[t] = f32x2{ -2.0f * qx[t], -2.0f * qx[t] };
        M2Y[t] = f32x2{ -2.0f * qy[t], -2.0f * qy[t] };
        M2Z[t] = f32x2{ -2.0f * qz[t], -2.0f * qz[t] };
        qnm[t] = -(qx[t]*qx[t] + qy[t]*qy[t] + qz[t]*qz[t]) + GATE_MARGIN;
        tau[t] = __builtin_inff(); th[t] = __builtin_inff();
        ts[t]  = __builtin_inff();
    }

    const int qb = b * NQ + (gg << 2);       // global query base
    if (h == 0 && lane == 0) {
        #pragma unroll
        for (int t = 0; t < 4; ++t) {
            out_pts[3 * (qb + t) + 0] = qx[t];
            out_pts[3 * (qb + t) + 1] = qy[t];
            out_pts[3 * (qb + t) + 2] = qz[t];
        }
    }

    // Cross-wave tau exchange (R11 protocol: stale reads are conservative).
    __shared__ float stau[2][4];
    if (lane == 0) {
        stau[h][0] = __builtin_inff(); stau[h][1] = __builtin_inff();
        stau[h][2] = __builtin_inff(); stau[h][3] = __builtin_inff();
    }
    __syncthreads();

    float ld = __builtin_inff();  int li = 0x7fffffff;

    unsigned o = h * HALF + 8 * (unsigned)lane;
    int pb = (int)o;

    PtBuf A, Bf;
    loadbuf(A, xs, ys, zs, o);
    for (int k = 0; k < ITERS_H; k += 2) {
        loadbuf(Bf, xs, ys, zs, o + 512);
        step4(A, pb, lane, M2X, M2Y, M2Z, qx, qy, qz, ld, li, tau, th, qnm, ts);
        if (lane == 0) {
            stau[h][0] = tau[0]; stau[h][1] = tau[1];
            stau[h][2] = tau[2]; stau[h][3] = tau[3];
        }
        #pragma unroll
        for (int t = 0; t < 4; ++t) {
            ts[t] = stau[h ^ 1][t];
            th[t] = fminf(tau[t], ts[t]) + qnm[t];
        }
        if (k + 2 < ITERS_H)
            loadbuf(A, xs, ys, zs, o + 1024);
        step4(Bf, pb + 512, lane, M2X, M2Y, M2Z, qx, qy, qz, ld, li, tau, th, qnm, ts);
        if (lane == 0) {
            stau[h][0] = tau[0]; stau[h][1] = tau[1];
            stau[h][2] = tau[2]; stau[h][3] = tau[3];
        }
        #pragma unroll
        for (int t = 0; t < 4; ++t) {
            ts[t] = stau[h ^ 1][t];
            th[t] = fminf(tau[t], ts[t]) + qnm[t];
        }
        o += 1024;
        pb += 1024;
    }

    // ---- exact rank-merge of the two halves' sorted 16-lists (4 queries) ----
    // Real keys distinct; fillers (inf, maxidx) tie -> never counted smaller,
    // and union holds >=16 reals per query -> fillers always pos>=16.
    __shared__ float sd[2 * 64];
    __shared__ int   si[2 * 64];
    sd[h * 64 + lane] = ld;
    si[h * 64 + lane] = li;
    __syncthreads();
    const int T  = lane >> 4;                // query within block
    const int r  = lane & 15;                // rank in own list
    const int pb2 = (h ^ 1) * 64 + (T << 4);
    int cnt = 0;
    #pragma unroll
    for (int t = 0; t < 16; ++t) {
        const float od = sd[pb2 + t];
        const int   oi = si[pb2 + t];
        cnt += (od < ld || (od == ld && oi < li)) ? 1 : 0;
    }
    const int pos = r + cnt;
    if (pos < KNN)
        out_idx[(size_t)(qb + T) * KNN + pos] = (float)li;
}

// ---------------- fallback: proven R9 kernel (AoS, scalar gate) ----------------
#define BLOCK 256
#define WPB   4
#define ITERS (NPTS / (64 * PPL))   // 64

__device__ __forceinline__ void load6(float4 dst[6], const float4* p) {
    #pragma unroll
    for (int t = 0; t < 6; ++t) dst[t] = p[t];
}

__device__ __forceinline__ void step2(const float4 c[6], int pb, int lane,
                                      float m2x0, float m2y0, float m2z0,
                                      float m2x1, float m2y1, float m2z1,
                                      float qx0, float qy0, float qz0,
                                      float qx1, float qy1, float qz1,
                                      float& ld, int& li,
                                      float& tau0, float& tau1,
                                      float& th0, float& th1,
                                      float qnm0, float qnm1)
{
    float px[PPL], py[PPL], pz[PPL];
    px[0] = c[0].x; py[0] = c[0].y; pz[0] = c[0].z;
    px[1] = c[0].w; py[1] = c[1].x; pz[1] = c[1].y;
    px[2] = c[1].z; py[2] = c[1].w; pz[2] = c[2].x;
    px[3] = c[2].y; py[3] = c[2].z; pz[3] = c[2].w;
    px[4] = c[3].x; py[4] = c[3].y; pz[4] = c[3].z;
    px[5] = c[3].w; py[5] = c[4].x; pz[5] = c[4].y;
    px[6] = c[4].z; py[6] = c[4].w; pz[6] = c[5].x;
    px[7] = c[5].y; py[7] = c[5].z; pz[7] = c[5].w;

    unsigned long long m0[PPL], m1[PPL], any = 0;
    #pragma unroll
    for (int j = 0; j < PPL; ++j) {
        const float s = __fmaf_rn(pz[j], pz[j],
                          __fmaf_rn(py[j], py[j], __fmul_rn(px[j], px[j])));
        float t0 = __fmaf_rn(px[j], m2x0, s);
        t0 = __fmaf_rn(py[j], m2y0, t0);
        t0 = __fmaf_rn(pz[j], m2z0, t0);
        m0[j] = __ballot(t0 <= th0);
        float t1 = __fmaf_rn(px[j], m2x1, s);
        t1 = __fmaf_rn(py[j], m2y1, t1);
        t1 = __fmaf_rn(pz[j], m2z1, t1);
        m1[j] = __ballot(t1 <= th1);
        any |= m0[j] | m1[j];
    }
    if (any) {
        #pragma unroll
        for (int j = 0; j < PPL; ++j) {
            if (m0[j]) {
                const float dx = __fadd_rn(px[j], -qx0);
                const float dy = __fadd_rn(py[j], -qy0);
                const float dz = __fadd_rn(pz[j], -qz0);
                const float d  = __fadd_rn(
                    __fadd_rn(__fmul_rn(dx, dx), __fmul_rn(dy, dy)),
                    __fmul_rn(dz, dz));
                insert_rt(0, d, pb + j, lane, ld, li, tau0, th0, qnm0,
                          __builtin_inff());
            }
        }
        #pragma unroll
        for (int j = 0; j < PPL; ++j) {
            if (m1[j]) {
                const float dx = __fadd_rn(px[j], -qx1);
                const float dy = __fadd_rn(py[j], -qy1);
                const float dz = __fadd_rn(pz[j], -qz1);
                const float d  = __fadd_rn(
                    __fadd_rn(__fmul_rn(dx, dx), __fmul_rn(dy, dy)),
                    __fmul_rn(dz, dz));
                insert_rt(1, d, pb + j, lane, ld, li, tau1, th1, qnm1,
                          __builtin_inff());
            }
        }
    }
}

__global__ __launch_bounds__(BLOCK) void knn_aos(const float* __restrict__ xyz,
                                                 float* __restrict__ out_idx,
                                                 float* __restrict__ out_pts)
{
    const int tid  = threadIdx.x;
    const int lane = tid & 63;
    const int wv   = tid >> 6;
    const int w    = blockIdx.x * WPB + wv;
    const int b    = w >> 10;
    const int pr   = w & 1023;
    const size_t base = (size_t)b * NPTS * 3;

    const int qp0 = pr << 5;
    const float qx0 = xyz[base + 3 * qp0 + 0];
    const float qy0 = xyz[base + 3 * qp0 + 1];
    const float qz0 = xyz[base + 3 * qp0 + 2];
    const float qx1 = xyz[base + 3 * qp0 + 48];
    const float qy1 = xyz[base + 3 * qp0 + 49];
    const float qz1 = xyz[base + 3 * qp0 + 50];

    const int g0 = b * NQ + (pr << 1);
    if (lane == 0) {
        out_pts[3 * g0 + 0] = qx0;
        out_pts[3 * g0 + 1] = qy0;
        out_pts[3 * g0 + 2] = qz0;
        out_pts[3 * g0 + 3] = qx1;
        out_pts[3 * g0 + 4] = qy1;
        out_pts[3 * g0 + 5] = qz1;
    }

    const float m2x0 = -2.0f * qx0, m2y0 = -2.0f * qy0, m2z0 = -2.0f * qz0;
    const float m2x1 = -2.0f * qx1, m2y1 = -2.0f * qy1, m2z1 = -2.0f * qz1;
    const float qnm0 = -(qx0 * qx0 + qy0 * qy0 + qz0 * qz0) + GATE_MARGIN;
    const float qnm1 = -(qx1 * qx1 + qy1 * qy1 + qz1 * qz1) + GATE_MARGIN;

    float ld = __builtin_inff();  int li = 0x7fffffff;
    float tau0 = __builtin_inff(), tau1 = __builtin_inff();
    float th0  = __builtin_inff(), th1  = __builtin_inff();

    const float4* lp = (const float4*)(xyz + base) + 6 * lane;

    float4 A[6], Bf[6];
    load6(A, lp);
    for (int k = 0; k < ITERS; k += 2) {
        load6(Bf, lp + 384);
        step2(A, (k << 9) + PPL * lane, lane,
              m2x0, m2y0, m2z0, m2x1, m2y1, m2z1,
              qx0, qy0, qz0, qx1, qy1, qz1,
              ld, li, tau0, tau1, th0, th1, qnm0, qnm1);
        if (k + 2 < ITERS)
            load6(A, lp + 768);
        step2(Bf, ((k + 1) << 9) + PPL * lane, lane,
              m2x0, m2y0, m2z0, m2x1, m2y1, m2z1,
              qx0, qy0, qz0, qx1, qy1, qz1,
              ld, li, tau0, tau1, th0, th1, qnm0, qnm1);
        lp += 768;
    }

    if (lane < 2 * KNN) {
        out_idx[(size_t)g0 * KNN + lane] = (float)li;
    }
}

extern "C" void kernel_launch(void* const* d_in, const int* in_sizes, int n_in,
                              void* d_out, int out_size, void* d_ws, size_t ws_size,
                              hipStream_t stream) {
    const float* xyz = (const float*)d_in[0];
    float* out = (float*)d_out;
    float* out_idx = out;                                 // NB*NQ*KNN floats
    float* out_pts = out + (size_t)NB * NQ * KNN;         // NB*NQ*3 floats

    const size_t ws_needed = (size_t)NB * 3 * NPTS * sizeof(float);  // 1.57 MB
    if (d_ws != nullptr && ws_size >= ws_needed) {
        float* wsp = (float*)d_ws;
        repack_soa<<<NB * NPTS / 4 / 256, 256, 0, stream>>>(xyz, wsp);
        knn4<<<NB * NQ / 4, 128, 0, stream>>>(wsp, out_idx, out_pts);
    } else {
        knn_aos<<<(NB * NQ / 2) / WPB, BLOCK, 0, stream>>>(xyz, out_idx, out_pts);
    }
}

// Round 25
// 183.297 us; speedup vs baseline: 1.3357x; 1.3357x over previous
//
#include <hip/hip_runtime.h>
#include <stdint.h>

// Problem constants: B=4, N=32768, K=16, nqueries=2048, stride=16.
// BEST-MEASURED KERNEL (R14: 141.6 us, five dispatches 140.4-141.8).
// Geometry: 2 queries per wave, full 32K stream, 256-thr blocks, 4096 waves.
// Gate: dot-product expansion, s=|p|^2 shared by both queries (11 ops/pt/pair);
// conservative margin; accepted lanes re-verified with the EXACT numpy-ordered
// distance (bit-exact results).
//
// Session map (9 measurements): non-split structures (R9/R14/R16/R18) all
// plateau at 142+-2 us (busy ~93 us, idle ~47 us at grid-capped 4 waves/SIMD).
// Splitting a query's stream across waves (R7/R11/R23) costs +45-55% busy in
// duplicated top-16 fill -- measured 3x, structural. Compiler reverts manual
// 3-buffer pipelines (VGPR=56 proves collapse; sched_barrier no-op). Packed
// gate (R18) cut gate ops but dur flat -> floor is insert chains + loads +
// ballots + latency. Next step beyond this plateau would be algorithmic
// (spatial pruning), not utilization.
#define NPTS  32768
#define NQ    2048
#define KNN   16
#define NB    4
#define BLOCK 256
#define WPB   4               // waves per block; 2 queries per wave
#define PPL   8               // points per lane per iteration
#define ITERS (NPTS / (64 * PPL))   // 64
#define GATE_MARGIN 5e-4f

__device__ __forceinline__ int dpp_shr1_i(int x) {
    // row_shr:1 within 16-lane rows; row-start lane keeps old (bound_ctrl=0)
    return __builtin_amdgcn_update_dpp(x, x, 0x111, 0xf, 0xf, false);
}
__device__ __forceinline__ float dpp_shr1_f(float x) {
    return __int_as_float(dpp_shr1_i(__float_as_int(x)));
}
__device__ __forceinline__ float readlane_f(float x, int l) {
    return __int_as_float(__builtin_amdgcn_readlane(__float_as_int(x), l));
}

// Exact distributed top-16 for query T (0/1): sorted list (ascending by
// (dist,idx)) in lanes 16T..16T+15; lane 16T+15 holds the exact threshold
// tau. d is the EXACT numpy distance. th = tau + qnm is the conservative
// dot-product-gate threshold (qnm = -|q|^2 + margin).
template <int T>
__device__ __forceinline__ void insert_all(float d, int p, int lane,
                                           float& ld, int& li, float& tau,
                                           float& th, float qnm)
{
    unsigned long long rem = __ballot(d <= tau);
    while (rem) {
        const int srcl = __ffsll(rem) - 1;           // wave-uniform
        const float wd = readlane_f(d, srcl);
        const int   wi = __builtin_amdgcn_readlane(p, srcl);
        const bool less = (ld < wd) || (ld == wd && li < wi);
        const unsigned long long lm = __ballot(less);
        const int pos = __popc((unsigned)((lm >> (16 * T)) & 0xffffull));
        const float pld = dpp_shr1_f(ld);
        const int   pli = dpp_shr1_i(li);
        if ((lane >> 4) == T) {
            const int gl = lane & 15;
            if (gl == pos)      { ld = wd;  li = wi;  }
            else if (gl > pos)  { ld = pld; li = pli; }
        }
        tau = readlane_f(ld, 16 * T + 15);
        th  = tau + qnm;                             // gate threshold update
        rem &= rem - 1;
        if (rem) rem &= __ballot(d <= tau);          // re-gate survivors (exact)
    }
}

__device__ __forceinline__ void load6(float4 dst[6], const float4* p) {
    #pragma unroll
    for (int t = 0; t < 6; ++t) dst[t] = p[t];
}

// One 512-point step: 8 pts/lane; shared |p|^2 + per-query 3-fma gate;
// exact recompute + exact insert for accepted slots.
__device__ __forceinline__ void step2(const float4 c[6], int pb, int lane,
                                      float m2x0, float m2y0, float m2z0,
                                      float m2x1, float m2y1, float m2z1,
                                      float qx0, float qy0, float qz0,
                                      float qx1, float qy1, float qz1,
                                      float& ld, int& li,
                                      float& tau0, float& tau1,
                                      float& th0, float& th1,
                                      float qnm0, float qnm1)
{
    float px[PPL], py[PPL], pz[PPL];                 // pure register renames
    px[0] = c[0].x; py[0] = c[0].y; pz[0] = c[0].z;
    px[1] = c[0].w; py[1] = c[1].x; pz[1] = c[1].y;
    px[2] = c[1].z; py[2] = c[1].w; pz[2] = c[2].x;
    px[3] = c[2].y; py[3] = c[2].z; pz[3] = c[2].w;
    px[4] = c[3].x; py[4] = c[3].y; pz[4] = c[3].z;
    px[5] = c[3].w; py[5] = c[4].x; pz[5] = c[4].y;
    px[6] = c[4].z; py[6] = c[4].w; pz[6] = c[5].x;
    px[7] = c[5].y; py[7] = c[5].z; pz[7] = c[5].w;

    unsigned long long m0[PPL], m1[PPL], any = 0;
    #pragma unroll
    for (int j = 0; j < PPL; ++j) {                  // 8 independent chains
        const float s = __fmaf_rn(pz[j], pz[j],
                          __fmaf_rn(py[j], py[j], __fmul_rn(px[j], px[j])));
        float t0 = __fmaf_rn(px[j], m2x0, s);
        t0 = __fmaf_rn(py[j], m2y0, t0);
        t0 = __fmaf_rn(pz[j], m2z0, t0);
        m0[j] = __ballot(t0 <= th0);
        float t1 = __fmaf_rn(px[j], m2x1, s);
        t1 = __fmaf_rn(py[j], m2y1, t1);
        t1 = __fmaf_rn(pz[j], m2z1, t1);
        m1[j] = __ballot(t1 <= th1);
        any |= m0[j] | m1[j];
    }
    if (any) {
        #pragma unroll
        for (int j = 0; j < PPL; ++j) {
            if (m0[j]) {                             // exact numpy distance
                const float dx = __fadd_rn(px[j], -qx0);
                const float dy = __fadd_rn(py[j], -qy0);
                const float dz = __fadd_rn(pz[j], -qz0);
                const float d  = __fadd_rn(
                    __fadd_rn(__fmul_rn(dx, dx), __fmul_rn(dy, dy)),
                    __fmul_rn(dz, dz));
                insert_all<0>(d, pb + j, lane, ld, li, tau0, th0, qnm0);
            }
        }
        #pragma unroll
        for (int j = 0; j < PPL; ++j) {
            if (m1[j]) {
                const float dx = __fadd_rn(px[j], -qx1);
                const float dy = __fadd_rn(py[j], -qy1);
                const float dz = __fadd_rn(pz[j], -qz1);
                const float d  = __fadd_rn(
                    __fadd_rn(__fmul_rn(dx, dx), __fmul_rn(dy, dy)),
                    __fmul_rn(dz, dz));
                insert_all<1>(d, pb + j, lane, ld, li, tau1, th1, qnm1);
            }
        }
    }
}

// 1024 blocks x 4 waves = 4096 waves. launch_bounds(256,4) caps VGPR at 128
// (cap ABOVE natural demand -> no spill; caps below demand caused the R3/R4
// spill disasters).
__global__ __launch_bounds__(BLOCK, 4) void knn_kernel(const float* __restrict__ xyz,
                                                       float* __restrict__ out_idx,
                                                       float* __restrict__ out_pts)
{
    const int tid  = threadIdx.x;
    const int lane = tid & 63;
    const int wv   = tid >> 6;
    const int w    = blockIdx.x * WPB + wv;          // wave id in [0, 4096)
    const int b    = w >> 10;
    const int pr   = w & 1023;                       // query pair
    const size_t base = (size_t)b * NPTS * 3;

    const int qp0 = pr << 5;                         // stride-16 subsample
    const float qx0 = xyz[base + 3 * qp0 + 0];
    const float qy0 = xyz[base + 3 * qp0 + 1];
    const float qz0 = xyz[base + 3 * qp0 + 2];
    const float qx1 = xyz[base + 3 * qp0 + 48];
    const float qy1 = xyz[base + 3 * qp0 + 49];
    const float qz1 = xyz[base + 3 * qp0 + 50];

    const int g0 = b * NQ + (pr << 1);
    if (lane == 0) {
        out_pts[3 * g0 + 0] = qx0;
        out_pts[3 * g0 + 1] = qy0;
        out_pts[3 * g0 + 2] = qz0;
        out_pts[3 * g0 + 3] = qx1;
        out_pts[3 * g0 + 4] = qy1;
        out_pts[3 * g0 + 5] = qz1;
    }

    // Gate constants: m2* = -2q*, qnm = -|q|^2 + margin.
    const float m2x0 = -2.0f * qx0, m2y0 = -2.0f * qy0, m2z0 = -2.0f * qz0;
    const float m2x1 = -2.0f * qx1, m2y1 = -2.0f * qy1, m2z1 = -2.0f * qz1;
    const float qnm0 = -(qx0 * qx0 + qy0 * qy0 + qz0 * qz0) + GATE_MARGIN;
    const float qnm1 = -(qx1 * qx1 + qy1 * qy1 + qz1 * qz1) + GATE_MARGIN;

    float ld = __builtin_inff();  int li = 0x7fffffff;
    float tau0 = __builtin_inff(), tau1 = __builtin_inff();
    float th0  = __builtin_inff(), th1  = __builtin_inff();

    // Lane's stream: 8 consecutive points (6 float4) per iteration.
    // Iteration i's lane data lives at lp0 + 384*i.
    const float4* lp0 = (const float4*)(xyz + base) + 6 * lane;

    // 3-stage software pipeline: buffer X holds iteration (3t + stage).
    float4 A[6], Bf[6], Cf[6];
    load6(A,  lp0);                                  // iter 0
    load6(Bf, lp0 + 384);                            // iter 1
    load6(Cf, lp0 + 768);                            // iter 2
    const float4* ld_ptr = lp0 + 3 * 384;            // next load: iter 3
    int pb = PPL * lane;                             // point base, iter 0

    for (int it = 0; it < 21; ++it) {                // iters 0..62
        step2(A, pb, lane,
              m2x0, m2y0, m2z0, m2x1, m2y1, m2z1,
              qx0, qy0, qz0, qx1, qy1, qz1,
              ld, li, tau0, tau1, th0, th1, qnm0, qnm1);
        pb += 512;
        load6(A, ld_ptr);  ld_ptr += 384;            // iter 3it+3 (<=63: valid)
        step2(Bf, pb, lane,
              m2x0, m2y0, m2z0, m2x1, m2y1, m2z1,
              qx0, qy0, qz0, qx1, qy1, qz1,
              ld, li, tau0, tau1, th0, th1, qnm0, qnm1);
        pb += 512;
        if (it < 20) load6(Bf, ld_ptr);              // iter 3it+4 (guard OOB)
        ld_ptr += 384;
        step2(Cf, pb, lane,
              m2x0, m2y0, m2z0, m2x1, m2y1, m2z1,
              qx0, qy0, qz0, qx1, qy1, qz1,
              ld, li, tau0, tau1, th0, th1, qnm0, qnm1);
        pb += 512;
        if (it < 20) load6(Cf, ld_ptr);              // iter 3it+5 (guard OOB)
        ld_ptr += 384;
    }
    // epilogue: iter 63 (loaded into A during it=20)
    step2(A, pb, lane,
          m2x0, m2y0, m2z0, m2x1, m2y1, m2z1,
          qx0, qy0, qz0, qx1, qy1, qz1,
          ld, li, tau0, tau1, th0, th1, qnm0, qnm1);

    // lanes 0..15: q0 ranks 0..15; lanes 16..31: q1 ranks (g1 = g0+1)
    if (lane < 2 * KNN) {
        out_idx[(size_t)g0 * KNN + lane] = (float)li;
    }
}

extern "C" void kernel_launch(void* const* d_in, const int* in_sizes, int n_in,
                              void* d_out, int out_size, void* d_ws, size_t ws_size,
                              hipStream_t stream) {
    const float* xyz = (const float*)d_in[0];
    float* out = (float*)d_out;
    float* out_idx = out;                                 // NB*NQ*KNN floats
    float* out_pts = out + (size_t)NB * NQ * KNN;         // NB*NQ*3 floats

    const int blocks = (NB * NQ / 2) / WPB;               // 1024
    knn_kernel<<<blocks, BLOCK, 0, stream>>>(xyz, out_idx, out_pts);
}